// Round 5
// baseline (350.607 us; speedup 1.0000x reference)
//
#include <hip/hip_runtime.h>

// ---------------------------------------------------------------------------
// SumAggregation v5: materialize Y, stream the final pass.
//   prep:   weights fp32->bf16 + zero stats       (1 dispatch)
//   trans:  feats -> fT bf16 (A x CIN) + Z-stats (atomics)  [merged groups]
//   finZ:   BN1 scale/shift
//   mid:    GEMM1 -> h (wave-private LDS) -> GEMM2 -> Y bf16 (ws) + Y-stats
//   finY:   BN2 scale/shift
//   final:  out = relu(bn(Y0))*p0 + relu(bn(Y1))*p1  + fused zero tail
//           (pure streaming: ~200MB @ HBM ceiling)
// ws usage ~96 MB (observed ws >= 512 MiB from harness fill).
// ---------------------------------------------------------------------------

#define AT 65536

typedef __bf16 bf16_t;
typedef bf16_t bf16x8 __attribute__((ext_vector_type(8)));
typedef bf16_t bf16x4 __attribute__((ext_vector_type(4)));
typedef float  f32x4  __attribute__((ext_vector_type(4)));

__device__ __forceinline__ f32x4 mfma16(bf16x8 a, bf16x8 b, f32x4 c) {
  return __builtin_amdgcn_mfma_f32_16x16x32_bf16(a, b, c, 0, 0, 0);
}

__device__ __forceinline__ float redcol16(float v) {
  v += __shfl_xor(v, 1, 64);
  v += __shfl_xor(v, 2, 64);
  v += __shfl_xor(v, 4, 64);
  v += __shfl_xor(v, 8, 64);
  return v;
}

// ---------------------------------------------------------------------------
// prep: weights -> bf16, plus zero the 1536-float stats block.
__global__ __launch_bounds__(256) void prep_weights(
    const float* __restrict__ Wa0, const float* __restrict__ Wa1,
    const float* __restrict__ Wb0, const float* __restrict__ Wb1,
    bf16_t* __restrict__ Wab0, bf16_t* __restrict__ Wab1,
    bf16_t* __restrict__ Wbb0, bf16_t* __restrict__ Wbb1,
    float* __restrict__ stats)
{
  const int i = threadIdx.x + blockIdx.x * 256;
  if (i < 8192)        Wab0[i]         = (bf16_t)Wa0[i];
  else if (i < 24576)  Wab1[i - 8192]  = (bf16_t)Wa1[i - 8192];
  else if (i < 57344)  Wbb0[i - 24576] = (bf16_t)Wb0[i - 24576];
  else if (i < 90112)  Wbb1[i - 57344] = (bf16_t)Wb1[i - 57344];
  else if (i < 91648)  stats[i - 90112] = 0.f;
}

// ---------------------------------------------------------------------------
// Transpose feats -> fT (A x CIN bf16) + Z-stats via MFMA, atomics.
template <int CIN>
__device__ __forceinline__ void trans_one(
    const float* __restrict__ feats, const bf16_t* __restrict__ Wab,
    float* __restrict__ zsum, float* __restrict__ zssq,
    bf16_t* __restrict__ fT, int blk, char* __restrict__ tile)
{
  constexpr int KS1  = CIN / 32;
  constexpr int GR   = CIN / 8;     // 16B granules per row
  constexpr int ROWB = CIN * 2;     // LDS row bytes
  const int tid = threadIdx.x, lane = tid & 63;
  const int lr = lane & 15, lk = lane >> 4, wid = tid >> 6;
  const int a0 = blk * 64;

  // batch-load feats (independent, all in flight)
  f32x4 v[CIN / 16];
  const int cb = tid >> 4, aq = (tid & 15) * 4;
#pragma unroll
  for (int cc = 0; cc < CIN / 16; ++cc)
    v[cc] = *reinterpret_cast<const f32x4*>(
        feats + (size_t)(cc * 16 + cb) * AT + a0 + aq);

  // bf16 convert + transposed LDS writes (16B-granule XOR swizzle)
#pragma unroll
  for (int cc = 0; cc < CIN / 16; ++cc) {
    const int c = cc * 16 + cb;
    const int gsw = c >> 3, cbyte = (c & 7) * 2;
#pragma unroll
    for (int i = 0; i < 4; ++i) {
      const int a = aq + i;
      *reinterpret_cast<bf16_t*>(
          tile + a * ROWB + ((gsw ^ (a & 7)) << 4) + cbyte) = (bf16_t)v[cc][i];
    }
  }
  __syncthreads();

  // fT row stores (bf16x8 lines)
  {
    const int g = tid % GR, ar = tid / GR;
#pragma unroll
    for (int i = 0; i < (GR * 64) / 256; ++i) {
      const int a = ar + (256 / GR) * i;
      const bf16x8 w = *reinterpret_cast<const bf16x8*>(
          tile + a * ROWB + ((g ^ (a & 7)) << 4));
      *reinterpret_cast<bf16x8*>(fT + (size_t)(a0 + a) * CIN + g * 8) = w;
    }
  }

  // Z-stats via MFMA on the LDS tile
  bf16x8 WaF[2][KS1];
#pragma unroll
  for (int mi = 0; mi < 2; ++mi) {
    const bf16_t* base = Wab + (size_t)((2 * wid + mi) * 16 + lr) * CIN + lk * 8;
#pragma unroll
    for (int ks = 0; ks < KS1; ++ks)
      WaF[mi][ks] = *reinterpret_cast<const bf16x8*>(base + ks * 32);
  }

  float zs[2][4] = {}, zq[2][4] = {};
#pragma unroll
  for (int nt = 0; nt < 4; ++nt) {
    const int col = lr + 16 * nt;
    f32x4 z0 = {0.f, 0.f, 0.f, 0.f}, z1 = {0.f, 0.f, 0.f, 0.f};
#pragma unroll
    for (int ks = 0; ks < KS1; ++ks) {
      const int g2 = ks * 4 + lk;
      const bf16x8 bfr = *reinterpret_cast<const bf16x8*>(
          tile + col * ROWB + ((g2 ^ (col & 7)) << 4));
      z0 = mfma16(WaF[0][ks], bfr, z0);
      z1 = mfma16(WaF[1][ks], bfr, z1);
    }
#pragma unroll
    for (int i = 0; i < 4; ++i) {
      zs[0][i] += z0[i]; zq[0][i] += z0[i] * z0[i];
      zs[1][i] += z1[i]; zq[1][i] += z1[i] * z1[i];
    }
  }
#pragma unroll
  for (int mi = 0; mi < 2; ++mi) {
#pragma unroll
    for (int i = 0; i < 4; ++i) {
      zs[mi][i] = redcol16(zs[mi][i]);
      zq[mi][i] = redcol16(zq[mi][i]);
    }
    float vs = zs[mi][0], vq = zq[mi][0];
    vs = ((lr & 3) == 1) ? zs[mi][1] : vs;  vq = ((lr & 3) == 1) ? zq[mi][1] : vq;
    vs = ((lr & 3) == 2) ? zs[mi][2] : vs;  vq = ((lr & 3) == 2) ? zq[mi][2] : vq;
    vs = ((lr & 3) == 3) ? zs[mi][3] : vs;  vq = ((lr & 3) == 3) ? zq[mi][3] : vq;
    const float vv = (lr & 4) ? vq : vs;
    if (lr < 8) {
      const int ch = (2 * wid + mi) * 16 + lk * 4 + (lr & 3);
      atomicAdd(((lr & 4) ? zssq : zsum) + ch, vv);
    }
  }
}

__global__ __launch_bounds__(256) void trans_stats_all(
    const float* __restrict__ feats0, const float* __restrict__ feats1,
    const bf16_t* __restrict__ Wab0, const bf16_t* __restrict__ Wab1,
    float* __restrict__ zsum, float* __restrict__ zssq,
    bf16_t* __restrict__ fT0, bf16_t* __restrict__ fT1)
{
  __shared__ __align__(16) char tile[64 * 256];
  if (blockIdx.x < 1024)
    trans_one<64>(feats0, Wab0, zsum, zssq, fT0, blockIdx.x, tile);
  else
    trans_one<128>(feats1, Wab1, zsum + 128, zssq + 128, fT1,
                   blockIdx.x - 1024, tile);
}

// ---------------------------------------------------------------------------
__global__ void finalize_stats(const float* __restrict__ sum,
                               const float* __restrict__ ssq,
                               const float* __restrict__ gamma0,
                               const float* __restrict__ beta0,
                               const float* __restrict__ gamma1,
                               const float* __restrict__ beta1,
                               float* __restrict__ scale,
                               float* __restrict__ shift, int nch)
{
  const int t = threadIdx.x;             // 2*nch threads
  const int g = t / nch;
  const int c = t - g * nch;
  const float inv = 1.f / 65536.f;
  const float mu  = sum[t] * inv;
  const float var = ssq[t] * inv - mu * mu;   // biased variance
  const float ga  = (g ? gamma1 : gamma0)[c];
  const float be  = (g ? beta1 : beta0)[c];
  const float sc  = ga * rsqrtf(var + 1e-5f);
  scale[t] = sc;
  shift[t] = be - mu * sc;
}

// ---------------------------------------------------------------------------
// GEMM1 one group, wave-private: 32 cols, 128 h-channels -> hw (8KB LDS).
template <int CIN>
__device__ __forceinline__ void gemm1_dev(
    const bf16_t* __restrict__ fT, const bf16_t* __restrict__ Wab,
    const float* __restrict__ scZ, const float* __restrict__ shZ,
    char* __restrict__ hw, int colbase, int lr, int lk)
{
  constexpr int KS = CIN / 32;

  bf16x8 bf[2][KS];
#pragma unroll
  for (int sub = 0; sub < 2; ++sub)
#pragma unroll
    for (int ks = 0; ks < KS; ++ks)
      bf[sub][ks] = *reinterpret_cast<const bf16x8*>(
          fT + (size_t)(colbase + sub * 16 + lr) * CIN + lk * 8 + ks * 32);

#pragma unroll 2
  for (int rb = 0; rb < 8; ++rb) {
    bf16x8 af[KS];
    const bf16_t* wa = Wab + (size_t)(rb * 16 + lr) * CIN + lk * 8;
#pragma unroll
    for (int ks = 0; ks < KS; ++ks)
      af[ks] = *reinterpret_cast<const bf16x8*>(wa + ks * 32);

    f32x4 acc[2];
    acc[0] = f32x4{0.f, 0.f, 0.f, 0.f};
    acc[1] = f32x4{0.f, 0.f, 0.f, 0.f};
#pragma unroll
    for (int ks = 0; ks < KS; ++ks) {
      acc[0] = mfma16(af[ks], bf[0][ks], acc[0]);
      acc[1] = mfma16(af[ks], bf[1][ks], acc[1]);
    }

    const f32x4 sv = *reinterpret_cast<const f32x4*>(scZ + rb * 16 + lk * 4);
    const f32x4 bv = *reinterpret_cast<const f32x4*>(shZ + rb * 16 + lk * 4);
#pragma unroll
    for (int sub = 0; sub < 2; ++sub) {
      bf16x4 hv;
#pragma unroll
      for (int i = 0; i < 4; ++i)
        hv[i] = (bf16_t)fmaxf(acc[sub][i] * sv[i] + bv[i], 0.f);
      const int col = sub * 16 + lr;
      const int g8  = rb * 2 + (lk >> 1);
      *reinterpret_cast<bf16x4*>(
          hw + col * 256 + ((g8 ^ (col & 7)) << 4) + ((lk & 1) << 3)) = hv;
    }
  }
}

// GEMM2 one group: read hw, write Y bf16 + Y-stat atomics.
__device__ __forceinline__ void gemm2_store(
    const char* __restrict__ hw, const bf16_t* __restrict__ Wbb,
    float* __restrict__ ysum, float* __restrict__ yssq,
    bf16_t* __restrict__ Y, int colbase, int lr, int lk)
{
#pragma unroll 2
  for (int rb2 = 0; rb2 < 16; ++rb2) {
    bf16x8 af[4];
    const bf16_t* w = Wbb + (size_t)(rb2 * 16 + lr) * 128 + lk * 8;
#pragma unroll
    for (int ks = 0; ks < 4; ++ks)
      af[ks] = *reinterpret_cast<const bf16x8*>(w + ks * 32);

    f32x4 acc[2];
    acc[0] = f32x4{0.f, 0.f, 0.f, 0.f};
    acc[1] = f32x4{0.f, 0.f, 0.f, 0.f};
#pragma unroll
    for (int ks2 = 0; ks2 < 4; ++ks2) {
#pragma unroll
      for (int sub = 0; sub < 2; ++sub) {
        const int col = sub * 16 + lr;
        const int off = col * 256 + (((ks2 * 4 + lk) ^ (col & 7)) << 4);
        const bf16x8 hf = *reinterpret_cast<const bf16x8*>(hw + off);
        acc[sub] = mfma16(af[ks2], hf, acc[sub]);
      }
    }

    // Y store (bf16, [ch][a])
#pragma unroll
    for (int sub = 0; sub < 2; ++sub) {
      const int a = colbase + sub * 16 + lr;
#pragma unroll
      for (int i = 0; i < 4; ++i)
        Y[(size_t)(rb2 * 16 + lk * 4 + i) * AT + a] = (bf16_t)acc[sub][i];
    }

    // Y-stats
    float s[4], q[4];
#pragma unroll
    for (int i = 0; i < 4; ++i) {
      s[i] = redcol16(acc[0][i] + acc[1][i]);
      q[i] = redcol16(acc[0][i] * acc[0][i] + acc[1][i] * acc[1][i]);
    }
    float vs = s[0], vq = q[0];
    vs = ((lr & 3) == 1) ? s[1] : vs;  vq = ((lr & 3) == 1) ? q[1] : vq;
    vs = ((lr & 3) == 2) ? s[2] : vs;  vq = ((lr & 3) == 2) ? q[2] : vq;
    vs = ((lr & 3) == 3) ? s[3] : vs;  vq = ((lr & 3) == 3) ? q[3] : vq;
    const float vv = (lr & 4) ? vq : vs;
    if (lr < 8) {
      const int ch = rb2 * 16 + lk * 4 + (lr & 3);
      atomicAdd(((lr & 4) ? yssq : ysum) + ch, vv);
    }
  }
}

// ---------------------------------------------------------------------------
__global__ __launch_bounds__(256) void mid_pass(
    const bf16_t* __restrict__ fT0, const bf16_t* __restrict__ fT1,
    const bf16_t* __restrict__ Wab0, const bf16_t* __restrict__ Wab1,
    const bf16_t* __restrict__ Wbb0, const bf16_t* __restrict__ Wbb1,
    const float* __restrict__ scaleZ, const float* __restrict__ shiftZ,
    float* __restrict__ ysum, float* __restrict__ yssq,
    bf16_t* __restrict__ Y0, bf16_t* __restrict__ Y1)
{
  __shared__ __align__(16) char hbuf[4][8192];   // wave-private h (32KB)
  const int tid = threadIdx.x, wid = tid >> 6, lane = tid & 63;
  const int lr = lane & 15, lk = lane >> 4;
  const int colbase = (int)blockIdx.x * 128 + wid * 32;
  char* hw = hbuf[wid];

  // group 0 (h reused wave-privately; same-wave LDS deps handled by lgkmcnt)
  gemm1_dev<64>(fT0, Wab0, scaleZ, shiftZ, hw, colbase, lr, lk);
  gemm2_store(hw, Wbb0, ysum, yssq, Y0, colbase, lr, lk);
  // group 1
  gemm1_dev<128>(fT1, Wab1, scaleZ + 128, shiftZ + 128, hw, colbase, lr, lk);
  gemm2_store(hw, Wbb1, ysum + 256, yssq + 256, Y1, colbase, lr, lk);
}

// ---------------------------------------------------------------------------
// final: out[b][ch][m] = relu(bn(Y0))*p0 + relu(bn(Y1))*p1 ; tail zeros.
__global__ __launch_bounds__(256) void final_pass(
    const bf16_t* __restrict__ Y0, const bf16_t* __restrict__ Y1,
    const float* __restrict__ prob0, const float* __restrict__ prob1,
    const float* __restrict__ scaleY, const float* __restrict__ shiftY,
    float* __restrict__ out)
{
  const int gid  = (int)blockIdx.x * 256 + threadIdx.x;
  const int row  = gid >> 10;            // b*256 + ch
  const int mseg = (gid & 1023) << 4;    // 16 m per thread
  const int b = row >> 8, ch = row & 255;
  const size_t a = ((size_t)b << 14) + mseg;

  const float s0 = scaleY[ch],       h0 = shiftY[ch];
  const float s1 = scaleY[256 + ch], h1 = shiftY[256 + ch];

  const bf16x8* y0p = reinterpret_cast<const bf16x8*>(Y0 + (size_t)ch * AT + a);
  const bf16x8* y1p = reinterpret_cast<const bf16x8*>(Y1 + (size_t)ch * AT + a);
  const bf16x8 y0v[2] = {y0p[0], y0p[1]};
  const bf16x8 y1v[2] = {y1p[0], y1p[1]};

  const f32x4* p0p = reinterpret_cast<const f32x4*>(prob0 + ((size_t)b << 15) + mseg);
  const f32x4* p1p = reinterpret_cast<const f32x4*>(prob1 + ((size_t)b << 15) + mseg);
  f32x4 p0v[4], p1v[4];
#pragma unroll
  for (int j = 0; j < 4; ++j) { p0v[j] = p0p[j]; p1v[j] = p1p[j]; }

  f32x4 o[4];
#pragma unroll
  for (int j = 0; j < 16; ++j) {
    const float v0 = fmaxf((float)y0v[j >> 3][j & 7] * s0 + h0, 0.f) * p0v[j >> 2][j & 3];
    const float v1 = fmaxf((float)y1v[j >> 3][j & 7] * s1 + h1, 0.f) * p1v[j >> 2][j & 3];
    o[j >> 2][j & 3] = v0 + v1;
  }

  float* ob = out + ((size_t)row << 15) + mseg;
  const f32x4 z = {0.f, 0.f, 0.f, 0.f};
#pragma unroll
  for (int j = 0; j < 4; ++j) {
    reinterpret_cast<f32x4*>(ob)[j] = o[j];
    reinterpret_cast<f32x4*>(ob + 16384)[j] = z;
  }
}

// ---------------------------------------------------------------------------
extern "C" void kernel_launch(void* const* d_in, const int* in_sizes, int n_in,
                              void* d_out, int out_size, void* d_ws, size_t ws_size,
                              hipStream_t stream)
{
  (void)in_sizes; (void)n_in; (void)out_size; (void)ws_size;
  const float* feats0 = (const float*)d_in[0];
  const float* feats1 = (const float*)d_in[1];
  const float* prob0  = (const float*)d_in[2];
  const float* prob1  = (const float*)d_in[3];
  const float* Wa0 = (const float*)d_in[6];
  const float* ga0 = (const float*)d_in[7];
  const float* ba0 = (const float*)d_in[8];
  const float* Wb0 = (const float*)d_in[9];
  const float* gb0 = (const float*)d_in[10];
  const float* bb0 = (const float*)d_in[11];
  const float* Wa1 = (const float*)d_in[12];
  const float* ga1 = (const float*)d_in[13];
  const float* ba1 = (const float*)d_in[14];
  const float* Wb1 = (const float*)d_in[15];
  const float* gb1 = (const float*)d_in[16];
  const float* bb1 = (const float*)d_in[17];

  float* out = (float*)d_out;
  char*  wsb = (char*)d_ws;
  float* ws  = (float*)d_ws;

  // stats block (zeroed by prep): zsum[256] zssq[256] ysum[512] yssq[512]
  float* zsum = ws;
  float* zssq = ws + 256;
  float* ysum = ws + 512;
  float* yssq = ws + 1024;
  // BN params
  float* scaleZ = ws + 1536;   // [256]
  float* shiftZ = ws + 1792;   // [256]
  float* scaleY = ws + 2048;   // [512]
  float* shiftY = ws + 2560;   // [512]
  // bf16 weights
  bf16_t* Wab0 = (bf16_t*)(wsb + (16  << 10));  // 128x64
  bf16_t* Wab1 = (bf16_t*)(wsb + (32  << 10));  // 128x128
  bf16_t* Wbb0 = (bf16_t*)(wsb + (64  << 10));  // 256x128
  bf16_t* Wbb1 = (bf16_t*)(wsb + (128 << 10));  // 256x128
  // big buffers
  bf16_t* fT0 = (bf16_t*)(wsb + (256 << 10));             // 65536x64   8MB
  bf16_t* fT1 = (bf16_t*)(wsb + (256 << 10) + (8 << 20)); // 65536x128 16MB
  bf16_t* Y0  = (bf16_t*)(wsb + (32ull << 20));           // 256x65536 32MB
  bf16_t* Y1  = (bf16_t*)(wsb + (64ull << 20));           // 256x65536 32MB

  prep_weights<<<358, 256, 0, stream>>>(Wa0, Wa1, Wb0, Wb1,
                                        Wab0, Wab1, Wbb0, Wbb1, zsum);

  trans_stats_all<<<2048, 256, 0, stream>>>(feats0, feats1, Wab0, Wab1,
                                            zsum, zssq, fT0, fT1);

  finalize_stats<<<1, 256, 0, stream>>>(zsum, zssq, ga0, ba0, ga1, ba1,
                                        scaleZ, shiftZ, 128);

  mid_pass<<<512, 256, 0, stream>>>(fT0, fT1, Wab0, Wab1, Wbb0, Wbb1,
                                    scaleZ, shiftZ, ysum, yssq, Y0, Y1);

  finalize_stats<<<1, 512, 0, stream>>>(ysum, yssq, gb0, bb0, gb1, bb1,
                                        scaleY, shiftY, 256);

  final_pass<<<4096, 256, 0, stream>>>(Y0, Y1, prob0, prob1,
                                       scaleY, shiftY, out);
}